// Round 18
// baseline (41.536 us; speedup 1.0000x reference)
//
#include <hip/hip_runtime.h>
#include <hip/hip_bf16.h>

// Problem constants (match reference)
constexpr int P = 8192;
constexpr int G = 4096;
constexpr float LOG2E = 1.4426950408889634f;

constexpr int NCH = 16;           // gaussian chunks (one wave covers 256 g)
constexpr int GPC = G / NCH;      // 256 gaussians per chunk
constexpr int NG = 4;             // gaussians per lane (one float4 per coef)
constexpr int PR = 256;           // point ranges
constexpr int PPW = P / PR;       // 32 points per wave
constexpr int NCOEF = 19;

// Packed fp32 pair -> VOP3P v_pk_{fma,mul,add}_f32 (verified -3.8us R12).
typedef float v2f __attribute__((ext_vector_type(2)));

// Single-instruction exp2 (v_exp_f32 IS 2^x; verified -4us R9).
__device__ __forceinline__ float fast_exp2(float x) {
  float r;
  asm("v_exp_f32 %0, %1" : "=v"(r) : "v"(x));
  return r;
}

// ---------------------------------------------------------------------------
// Kernel 1: per-Gaussian precompute -> SoA soa[k*G + g], k = 0..18:
//   0..2: mean xyz; 3..5: w00,w11,w22; 6..8: w01,w02,w12 (off-diag, 2x and
//   -0.5*log2e folded); 9: a0; 10..12: a1,a2,a3; 13..15: qxy,qyz,qxz;
//   16..18: qxx,qyy,qzz.  SoA so each lane's float4 gathers 4 consecutive
//   gaussians' coefficient k with one coalesced dwordx4.
// ---------------------------------------------------------------------------
__global__ __launch_bounds__(256) void precomp_kernel(
    const float* __restrict__ mean, const float* __restrict__ fdc,
    const float* __restrict__ frest, const float* __restrict__ scal,
    const float* __restrict__ rot, const float* __restrict__ opac,
    float* __restrict__ soa) {
  int g = blockIdx.x * blockDim.x + threadIdx.x;
  if (g >= G) return;

  float qr = rot[g * 4 + 0], qx = rot[g * 4 + 1];
  float qy = rot[g * 4 + 2], qz = rot[g * 4 + 3];
  float qn = 1.0f / sqrtf(qr * qr + qx * qx + qy * qy + qz * qz);
  qr *= qn; qx *= qn; qy *= qn; qz *= qn;

  float R00 = 1.f - 2.f * (qy * qy + qz * qz);
  float R01 = 2.f * (qx * qy - qr * qz);
  float R02 = 2.f * (qx * qz + qr * qy);
  float R10 = 2.f * (qx * qy + qr * qz);
  float R11 = 1.f - 2.f * (qx * qx + qz * qz);
  float R12 = 2.f * (qy * qz - qr * qx);
  float R20 = 2.f * (qx * qz - qr * qy);
  float R21 = 2.f * (qy * qz + qr * qx);
  float R22 = 1.f - 2.f * (qx * qx + qy * qy);

  float sc0 = expf(scal[g * 3 + 0]);
  float sc1 = expf(scal[g * 3 + 1]);
  float sc2 = expf(scal[g * 3 + 2]);
  float iv0 = 1.0f / (sc0 * sc0);
  float iv1 = 1.0f / (sc1 * sc1);
  float iv2 = 1.0f / (sc2 * sc2);

  float s00 = R00 * R00 * iv0 + R01 * R01 * iv1 + R02 * R02 * iv2;
  float s11 = R10 * R10 * iv0 + R11 * R11 * iv1 + R12 * R12 * iv2;
  float s22 = R20 * R20 * iv0 + R21 * R21 * iv1 + R22 * R22 * iv2;
  float s01 = R00 * R10 * iv0 + R01 * R11 * iv1 + R02 * R12 * iv2;
  float s02 = R00 * R20 * iv0 + R01 * R21 * iv1 + R02 * R22 * iv2;
  float s12 = R10 * R20 * iv0 + R11 * R21 * iv1 + R12 * R22 * iv2;

  const float kD = -0.5f * LOG2E;
  const float kO = -LOG2E;

  float alpha = 1.0f / (1.0f + expf(-opac[g]));

  const float C0 = 0.28209479177387814f;
  const float C1 = 0.4886025119029199f;
  float a0 = C0 * fdc[g] * alpha;
  float a1 = -C1 * frest[g * 8 + 0] * alpha;
  float a2 =  C1 * frest[g * 8 + 1] * alpha;
  float a3 = -C1 * frest[g * 8 + 2] * alpha;
  float a4 =  1.0925484305920792f  * frest[g * 8 + 3] * alpha;
  float a5 = -1.0925484305920792f  * frest[g * 8 + 4] * alpha;
  float a6 =  0.31539156525252005f * frest[g * 8 + 5] * alpha;
  float a7 = -1.0925484305920792f  * frest[g * 8 + 6] * alpha;
  float a8 =  0.5462742152960396f  * frest[g * 8 + 7] * alpha;

  soa[0 * G + g]  = mean[g * 3 + 0];
  soa[1 * G + g]  = mean[g * 3 + 1];
  soa[2 * G + g]  = mean[g * 3 + 2];
  soa[3 * G + g]  = kD * s00;
  soa[4 * G + g]  = kD * s11;
  soa[5 * G + g]  = kD * s22;
  soa[6 * G + g]  = kO * s01;
  soa[7 * G + g]  = kO * s02;
  soa[8 * G + g]  = kO * s12;
  soa[9 * G + g]  = a0;
  soa[10 * G + g] = a1;
  soa[11 * G + g] = a2;
  soa[12 * G + g] = a3;
  soa[13 * G + g] = a4;          // qxy
  soa[14 * G + g] = a5;          // qyz
  soa[15 * G + g] = a7;          // qxz
  soa[16 * G + g] = a8 - a6;     // qxx
  soa[17 * G + g] = -a8 - a6;    // qyy
  soa[18 * G + g] = 2.f * a6;    // qzz
}

// ---------------------------------------------------------------------------
// Kernel 2: LANE-TRANSPOSED main loop. Wave w: gaussian chunk c = w/PR
// (lane owns NG=4 gaussians' coefficients in 19 float4 = 76 VGPR, loaded
// once, coalesced), point range r = w%PR (32 points, wave-uniform -> the
// compiler scalarizes pos loads to s_load; points feed v_pk ops as the
// free/splat operand). ZERO ds_read in the loop -- the 12.8us/CU LDS pipe
// (R12-R17's dominant serialized term) is eliminated. Per point: 2 packed
// evals (identical per-pair VALU/trans as champion) + 6-step __shfl_xor
// tree (ds_swizzle on the now-idle LDS path) -> lane 0 writes
// partial[c][p]. Grid: 16 chunks x 256 ranges = 4096 waves = 1024 blocks
// (4/CU, 16 waves/CU). Deterministic: fixed chunk/tree combine order.
// ---------------------------------------------------------------------------
__global__ __launch_bounds__(256) void main_kernel(
    const float* __restrict__ pos, const float* __restrict__ soa,
    float* __restrict__ partial) {
  const int t = threadIdx.x;
  const int lane = t & 63;
  const int w = blockIdx.x * 4 + (t >> 6);
  const int c = w >> 8;                 // w / PR
  const int r = w & (PR - 1);
  const int g0 = c * GPC + lane * NG;
  const int pbase = r * PPW;

  float4 cf[NCOEF];
#pragma unroll
  for (int k = 0; k < NCOEF; ++k)
    cf[k] = *reinterpret_cast<const float4*>(soa + (size_t)k * G + g0);

// v2f view of coefficient k for gaussian-pair pi (0: .xy, 1: .zw) --
// pi is unroll-static so this is pure register aliasing.
#define CV(k) (pi == 0 ? (v2f){cf[k].x, cf[k].y} : (v2f){cf[k].z, cf[k].w})

  for (int pass = 0; pass < PPW / 2; ++pass) {
    const int p0 = pbase + pass * 2;

    float qs0[3], qs1[3];
    qs0[0] = pos[(p0 + 0) * 3 + 0] * 2.0f - 1.0f;
    qs0[1] = pos[(p0 + 0) * 3 + 1] * 2.0f - 1.0f;
    qs0[2] = pos[(p0 + 0) * 3 + 2] * 2.0f - 1.0f;
    qs1[0] = pos[(p0 + 1) * 3 + 0] * 2.0f - 1.0f;
    qs1[1] = pos[(p0 + 1) * 3 + 1] * 2.0f - 1.0f;
    qs1[2] = pos[(p0 + 1) * 3 + 2] * 2.0f - 1.0f;

    v2f acc0 = {0.f, 0.f}, acc1 = {0.f, 0.f};

#pragma unroll
    for (int j = 0; j < 2; ++j) {
      const float* qs = (j == 0) ? qs0 : qs1;
      const v2f qx = {qs[0], qs[0]};
      const v2f qy = {qs[1], qs[1]};
      const v2f qz = {qs[2], qs[2]};
      v2f accl = {0.f, 0.f};

#pragma unroll
      for (int pi = 0; pi < 2; ++pi) {
        const v2f dx = qx - CV(0);
        const v2f dy = qy - CV(1);
        const v2f dz = qz - CV(2);
        const v2f dxx = dx * dx, dyy = dy * dy, dzz = dz * dz;
        const v2f dxdy = dx * dy, dxdz = dx * dz, dydz = dy * dz;
        const v2f d2 = dxx + dyy + dzz;

        v2f m = CV(3) * dxx;
        m = CV(4) * dyy + m;
        m = CV(5) * dzz + m;
        m = CV(6) * dxdy + m;
        m = CV(7) * dxdz + m;
        m = CV(8) * dydz + m;
        v2f gauss;
        gauss.x = fast_exp2(m.x);
        gauss.y = fast_exp2(m.y);

        const v2f d2c = __builtin_elementwise_max(d2, (v2f){1e-16f, 1e-16f});
        v2f inv;
        inv.x = __builtin_amdgcn_rsqf(d2c.x);
        inv.y = __builtin_amdgcn_rsqf(d2c.y);
        const v2f inv2 = inv * inv;

        v2f lin = CV(10) * dy;             // a1*dy
        lin = CV(11) * dz + lin;           // a2*dz
        lin = CV(12) * dx + lin;           // a3*dx

        v2f quad = CV(13) * dxdy;          // qxy
        quad = CV(14) * dydz + quad;       // qyz
        quad = CV(15) * dxdz + quad;       // qxz
        quad = CV(16) * dxx + quad;        // qxx
        quad = CV(17) * dyy + quad;        // qyy
        quad = CV(18) * dzz + quad;        // qzz

        v2f feat = inv * lin + CV(9);      // a0 + inv*lin
        feat = inv2 * quad + feat;

        accl = gauss * feat + accl;
      }
      if (j == 0) acc0 = accl; else acc1 = accl;
    }

    // wave reduction: each lane holds 4 gaussians' sum for each point
    float s0 = acc0.x + acc0.y;
    float s1 = acc1.x + acc1.y;
#pragma unroll
    for (int md = 1; md < 64; md <<= 1) {
      s0 += __shfl_xor(s0, md, 64);
      s1 += __shfl_xor(s1, md, 64);
    }
    if (lane == 0) {
      partial[(size_t)c * P + p0 + 0] = s0;
      partial[(size_t)c * P + p0 + 1] = s1;
    }
  }
#undef CV
}

// ---------------------------------------------------------------------------
// 16-way reduction over partial[NCH][P] (R7's proven two-level shape).
// 128 blocks x 256 thr; slice s = t>>6 sums c in [s*4, s*4+4) for point
// p = blk*64 + (t&63). Fixed combine order -> deterministic.
// ---------------------------------------------------------------------------
__global__ __launch_bounds__(256) void reduce_kernel(
    const float* __restrict__ partial, float* __restrict__ out) {
  __shared__ float red[4][64];
  const int t = threadIdx.x;
  const int lane = t & 63;
  const int s = t >> 6;
  const int p = blockIdx.x * 64 + lane;
  const int cbase = s * 4;

  float a0 = partial[(size_t)(cbase + 0) * P + p];
  float a1 = partial[(size_t)(cbase + 1) * P + p];
  float a2 = partial[(size_t)(cbase + 2) * P + p];
  float a3 = partial[(size_t)(cbase + 3) * P + p];
  red[s][lane] = (a0 + a1) + (a2 + a3);
  __syncthreads();

  if (t < 64) {
    out[p] = (red[0][lane] + red[1][lane]) + (red[2][lane] + red[3][lane]);
  }
}

extern "C" void kernel_launch(void* const* d_in, const int* in_sizes, int n_in,
                              void* d_out, int out_size, void* d_ws, size_t ws_size,
                              hipStream_t stream) {
  const float* pos   = (const float*)d_in[0];  // position_rx (P,3)
  const float* mean  = (const float*)d_in[1];  // mean (G,3)
  const float* fdc   = (const float*)d_in[2];  // features_dc (G,1,1)
  const float* frest = (const float*)d_in[3];  // features_rest (G,1,8)
  const float* scal  = (const float*)d_in[4];  // scaling (G,3)
  const float* rot   = (const float*)d_in[5];  // rotation (G,4)
  const float* opac  = (const float*)d_in[6];  // opacity (G,1)
  float* out = (float*)d_out;                  // (P,1) fp32

  float* soa = (float*)d_ws;                                     // 19*G*4 = 304 KB
  float* partial = (float*)((char*)d_ws + (size_t)NCOEF * G * sizeof(float));  // 512 KB

  precomp_kernel<<<G / 256, 256, 0, stream>>>(mean, fdc, frest, scal, rot, opac, soa);
  main_kernel<<<NCH * PR / 4, 256, 0, stream>>>(pos, soa, partial);
  reduce_kernel<<<P / 64, 256, 0, stream>>>(partial, out);
}

// Round 19
// 30.897 us; speedup vs baseline: 1.3443x; 1.3443x over previous
//
#include <hip/hip_runtime.h>
#include <hip/hip_bf16.h>

// Problem constants (match reference)
constexpr int P = 8192;
constexpr int G = 4096;
constexpr int BLK = 256;
constexpr int GSPLIT = 128;         // champion geometry (R12, 30.9us)
constexpr int CHUNK = G / GSPLIT;   // 32 gaussians per chunk
constexpr int PPT = 4;              // points per thread (2 packed halves)
constexpr int NH = PPT / 2;
constexpr int PBLK = BLK * PPT;     // 1024 points per block
constexpr float LOG2E = 1.4426950408889634f;

// Packed fp32 pair -> VOP3P v_pk_{fma,mul,add}_f32. Session finding: packs
// ISSUE SLOTS, not FLOP rate (157.3TF = scalar-rate ALU) -- R12's -3.8us was
// instruction-count relief. Kernel is fp32-VALU-execution-bound.
typedef float v2f __attribute__((ext_vector_type(2)));

// Single-instruction exp2 (v_exp_f32 IS 2^x; verified -4us R9 vs __ocml).
__device__ __forceinline__ float fast_exp2(float x) {
  float r;
  asm("v_exp_f32 %0, %1" : "=v"(r) : "v"(x));
  return r;
}

// ---------------------------------------------------------------------------
// CHAMPION (R12): fused precompute + LDS-broadcast + packed pair loop.
// Grid = (8, 128) = 1024 blocks, 4/CU, 16 waves/CU.
// Session probe matrix (main ~26us invariant under): LDS traffic x0.5 (R13/
// R14), occupancy 8..32 waves/CU (R13/R16), SGPR coefficient routing (R11/
// R15), lane-transpose (R18), unroll 4 (R17). Moves 1:1 with VALU
// instruction cuts (R9 exp2: -4us, R12 packing: -3.8us). Conclusion:
// fp32-ALU-execution-bound + ~1.5x stall exposure; no remaining algebraic
// or parallelism lever at HIP level.
// Per-gaussian coefficients (5 x float4 in LDS, broadcast ds_read_b128):
//   v0: mean.x, mean.y, mean.z, w00
//   v1: w11, w22, w01, w02
//   v2: w12, a0, a1, a2
//   v3: a3, qxy, qyz, qxz
//   v4: qxx, qyy, qzz, 0
// gauss = exp2(w00 dxx + w11 dyy + w22 dzz + w01 dxdy + w02 dxdz + w12 dydz)
// feat  = a0 + inv*lin + inv2*quad  (SH folded onto the same 6 monomials)
// ---------------------------------------------------------------------------
__global__ __launch_bounds__(BLK) void fused_main(
    const float* __restrict__ pos,
    const float* __restrict__ mean, const float* __restrict__ fdc,
    const float* __restrict__ frest, const float* __restrict__ scal,
    const float* __restrict__ rot, const float* __restrict__ opac,
    float* __restrict__ partial) {
  __shared__ float4 sg[CHUNK * 5];

  const int t = threadIdx.x;
  const int c = blockIdx.y;
  const int pbase = blockIdx.x * PBLK + t;

  // Points packed in pairs; loads issued first to overlap the precompute.
  v2f pxv[NH], pyv[NH], pzv[NH], accv[NH];
#pragma unroll
  for (int h = 0; h < NH; ++h) {
    const int pA = pbase + (2 * h + 0) * BLK;
    const int pB = pbase + (2 * h + 1) * BLK;
    v2f x = {pos[pA * 3 + 0], pos[pB * 3 + 0]};
    v2f y = {pos[pA * 3 + 1], pos[pB * 3 + 1]};
    v2f z = {pos[pA * 3 + 2], pos[pB * 3 + 2]};
    pxv[h] = x * 2.0f - 1.0f;
    pyv[h] = y * 2.0f - 1.0f;
    pzv[h] = z * 2.0f - 1.0f;
    accv[h] = (v2f){0.f, 0.f};
  }

  // In-block precompute of this chunk's 32 gaussians (8x redundant across
  // blockIdx.x; ~500 cycles, negligible).
  if (t < CHUNK) {
    const int g = c * CHUNK + t;

    float qr = rot[g * 4 + 0], qx = rot[g * 4 + 1];
    float qy = rot[g * 4 + 2], qz = rot[g * 4 + 3];
    float qn = 1.0f / sqrtf(qr * qr + qx * qx + qy * qy + qz * qz);
    qr *= qn; qx *= qn; qy *= qn; qz *= qn;

    float R00 = 1.f - 2.f * (qy * qy + qz * qz);
    float R01 = 2.f * (qx * qy - qr * qz);
    float R02 = 2.f * (qx * qz + qr * qy);
    float R10 = 2.f * (qx * qy + qr * qz);
    float R11 = 1.f - 2.f * (qx * qx + qz * qz);
    float R12 = 2.f * (qy * qz - qr * qx);
    float R20 = 2.f * (qx * qz - qr * qy);
    float R21 = 2.f * (qy * qz + qr * qx);
    float R22 = 1.f - 2.f * (qx * qx + qy * qy);

    float sc0 = expf(scal[g * 3 + 0]);
    float sc1 = expf(scal[g * 3 + 1]);
    float sc2 = expf(scal[g * 3 + 2]);
    float iv0 = 1.0f / (sc0 * sc0);
    float iv1 = 1.0f / (sc1 * sc1);
    float iv2 = 1.0f / (sc2 * sc2);

    float s00 = R00 * R00 * iv0 + R01 * R01 * iv1 + R02 * R02 * iv2;
    float s11 = R10 * R10 * iv0 + R11 * R11 * iv1 + R12 * R12 * iv2;
    float s22 = R20 * R20 * iv0 + R21 * R21 * iv1 + R22 * R22 * iv2;
    float s01 = R00 * R10 * iv0 + R01 * R11 * iv1 + R02 * R12 * iv2;
    float s02 = R00 * R20 * iv0 + R01 * R21 * iv1 + R02 * R22 * iv2;
    float s12 = R10 * R20 * iv0 + R11 * R21 * iv1 + R12 * R22 * iv2;

    const float kD = -0.5f * LOG2E;
    const float kO = -LOG2E;

    float alpha = 1.0f / (1.0f + expf(-opac[g]));

    const float C0 = 0.28209479177387814f;
    const float C1 = 0.4886025119029199f;
    float a0 = C0 * fdc[g] * alpha;
    float a1 = -C1 * frest[g * 8 + 0] * alpha;
    float a2 =  C1 * frest[g * 8 + 1] * alpha;
    float a3 = -C1 * frest[g * 8 + 2] * alpha;
    float a4 =  1.0925484305920792f  * frest[g * 8 + 3] * alpha;
    float a5 = -1.0925484305920792f  * frest[g * 8 + 4] * alpha;
    float a6 =  0.31539156525252005f * frest[g * 8 + 5] * alpha;
    float a7 = -1.0925484305920792f  * frest[g * 8 + 6] * alpha;
    float a8 =  0.5462742152960396f  * frest[g * 8 + 7] * alpha;

    float mx = mean[g * 3 + 0], my = mean[g * 3 + 1], mz = mean[g * 3 + 2];

    sg[t * 5 + 0] = make_float4(mx, my, mz, kD * s00);
    sg[t * 5 + 1] = make_float4(kD * s11, kD * s22, kO * s01, kO * s02);
    sg[t * 5 + 2] = make_float4(kO * s12, a0, a1, a2);
    sg[t * 5 + 3] = make_float4(a3, a4, a5, a7);                    // a3,qxy,qyz,qxz
    sg[t * 5 + 4] = make_float4(a8 - a6, -a8 - a6, 2.f * a6, 0.f);  // qxx,qyy,qzz
  }

  __syncthreads();

#pragma unroll 2
  for (int gi = 0; gi < CHUNK; ++gi) {
    const float4 v0 = sg[gi * 5 + 0];
    const float4 v1 = sg[gi * 5 + 1];
    const float4 v2 = sg[gi * 5 + 2];
    const float4 v3 = sg[gi * 5 + 3];
    const float4 v4 = sg[gi * 5 + 4];

#pragma unroll
    for (int h = 0; h < NH; ++h) {
      // scalar coefficients splat across the packed pair -> v_pk_* ops
      const v2f dx = pxv[h] - v0.x;
      const v2f dy = pyv[h] - v0.y;
      const v2f dz = pzv[h] - v0.z;
      const v2f dxx = dx * dx, dyy = dy * dy, dzz = dz * dz;
      const v2f dxdy = dx * dy, dxdz = dx * dz, dydz = dy * dz;
      const v2f d2 = dxx + dyy + dzz;

      v2f m = v0.w * dxx;
      m = v1.x * dyy + m;
      m = v1.y * dzz + m;
      m = v1.z * dxdy + m;
      m = v1.w * dxdz + m;
      m = v2.x * dydz + m;
      v2f gauss;
      gauss.x = fast_exp2(m.x);
      gauss.y = fast_exp2(m.y);

      const v2f d2c = __builtin_elementwise_max(d2, (v2f){1e-16f, 1e-16f});
      v2f inv;
      inv.x = __builtin_amdgcn_rsqf(d2c.x);
      inv.y = __builtin_amdgcn_rsqf(d2c.y);
      const v2f inv2 = inv * inv;

      v2f lin = v2.z * dy;                 // a1*dy
      lin = v2.w * dz + lin;               // a2*dz
      lin = v3.x * dx + lin;               // a3*dx

      v2f quad = v3.y * dxdy;              // qxy*dxdy
      quad = v3.z * dydz + quad;           // qyz*dydz
      quad = v3.w * dxdz + quad;           // qxz*dxdz
      quad = v4.x * dxx + quad;            // qxx*dxx
      quad = v4.y * dyy + quad;            // qyy*dyy
      quad = v4.z * dzz + quad;            // qzz*dzz

      v2f feat = inv * lin + v2.y;         // a0 + inv*lin
      feat = inv2 * quad + feat;

      accv[h] = gauss * feat + accv[h];
    }
  }

#pragma unroll
  for (int h = 0; h < NH; ++h) {
    partial[(size_t)c * P + pbase + (2 * h + 0) * BLK] = accv[h].x;
    partial[(size_t)c * P + pbase + (2 * h + 1) * BLK] = accv[h].y;
  }
}

// ---------------------------------------------------------------------------
// Two-level parallel reduction over GSPLIT=128 partials (R7 champion).
// 128 blocks x 256 thr; slice s = t>>6 sums contiguous c-range
// [s*32, s*32+32) for point p = blk*64 + (t&63), 4 accumulator chains.
// Fixed combine order -> deterministic.
// ---------------------------------------------------------------------------
__global__ __launch_bounds__(256) void reduce_kernel(
    const float* __restrict__ partial, float* __restrict__ out) {
  __shared__ float red[4][64];
  const int t = threadIdx.x;
  const int lane = t & 63;
  const int s = t >> 6;
  const int p = blockIdx.x * 64 + lane;
  const int cbase = s * 32;

  float a0 = 0.f, a1 = 0.f, a2 = 0.f, a3 = 0.f;
#pragma unroll
  for (int j = 0; j < 32; j += 4) {
    a0 += partial[(size_t)(cbase + j + 0) * P + p];
    a1 += partial[(size_t)(cbase + j + 1) * P + p];
    a2 += partial[(size_t)(cbase + j + 2) * P + p];
    a3 += partial[(size_t)(cbase + j + 3) * P + p];
  }
  red[s][lane] = (a0 + a1) + (a2 + a3);
  __syncthreads();

  if (t < 64) {
    out[p] = (red[0][lane] + red[1][lane]) + (red[2][lane] + red[3][lane]);
  }
}

extern "C" void kernel_launch(void* const* d_in, const int* in_sizes, int n_in,
                              void* d_out, int out_size, void* d_ws, size_t ws_size,
                              hipStream_t stream) {
  const float* pos   = (const float*)d_in[0];  // position_rx (P,3)
  const float* mean  = (const float*)d_in[1];  // mean (G,3)
  const float* fdc   = (const float*)d_in[2];  // features_dc (G,1,1)
  const float* frest = (const float*)d_in[3];  // features_rest (G,1,8)
  const float* scal  = (const float*)d_in[4];  // scaling (G,3)
  const float* rot   = (const float*)d_in[5];  // rotation (G,4)
  const float* opac  = (const float*)d_in[6];  // opacity (G,1)
  float* out = (float*)d_out;                  // (P,1) fp32

  float* partial = (float*)d_ws;               // GSPLIT*P*4 = 4 MB

  fused_main<<<dim3(P / PBLK, GSPLIT), BLK, 0, stream>>>(
      pos, mean, fdc, frest, scal, rot, opac, partial);
  reduce_kernel<<<P / 64, 256, 0, stream>>>(partial, out);
}